// Round 9
// baseline (139.428 us; speedup 1.0000x reference)
//
#include <hip/hip_runtime.h>

// Flip to 0 if absmax fails large: selects legacy (non-partitionable) JAX threefry stream.
#define JAX_THREEFRY_PARTITIONABLE 1

namespace {

constexpr int BN   = 2;      // batch
constexpr int C0   = 64;
constexpr int HH   = 100;
constexpr int WWW  = 100;
constexpr int LL   = 10000;  // H*W
constexpr int TL   = 20000;  // 2L
constexpr int CHK  = 144;
constexpr int NCHK = 139;    // (TL+16)/144
constexpr int NPAD = 16;
constexpr int WINR = 432;    // 3*144

// ws layout in float slots
constexpr int OFF_HT0  = 0;                    // conv1 partial kq=0 [4][16][10000]
constexpr int OFF_HT1  = OFF_HT0 + 640000;     // kq=1
constexpr int OFF_HT2  = OFF_HT1 + 640000;     // kq=2
constexpr int OFF_HT3  = OFF_HT2 + 640000;     // kq=3
constexpr int OFF_F    = OFF_HT3 + 640000;     // F [2][20000][16]
constexpr int OFF_SC   = OFF_F + 640000;       // SC [2][136]
constexpr int OFF_CODE = OFF_SC + 272;         // codes u8 [8][20000]
constexpr int OFF_RANK = OFF_CODE + 40000;     // rank int [8][20000]
constexpr int OFF_N0   = OFF_RANK + 160000;    // n0 int [8][139]
constexpr int OFF_INV  = OFF_N0 + 1112;        // inv int [10000]

__device__ __forceinline__ unsigned rotl32(unsigned v, int r) {
  return (v << r) | (v >> (32 - r));
}

// JAX threefry2x32, 20 rounds, key injection every 4.
__device__ void tf2x32(unsigned k0, unsigned k1, unsigned x0, unsigned x1,
                       unsigned& o0, unsigned& o1) {
  unsigned ks2 = k0 ^ k1 ^ 0x1BD11BDAu;
  x0 += k0; x1 += k1;
#define TFR(r) { x0 += x1; x1 = rotl32(x1, r); x1 ^= x0; }
  TFR(13) TFR(15) TFR(26) TFR(6)  x0 += k1;  x1 += ks2 + 1u;
  TFR(17) TFR(29) TFR(16) TFR(24) x0 += ks2; x1 += k0 + 2u;
  TFR(13) TFR(15) TFR(26) TFR(6)  x0 += k0;  x1 += k1 + 3u;
  TFR(17) TFR(29) TFR(16) TFR(24) x0 += k1;  x1 += ks2 + 4u;
  TFR(13) TFR(15) TFR(26) TFR(6)  x0 += ks2; x1 += k0 + 5u;
#undef TFR
  o0 = x0; o1 = x1;
}

// XLA's ErfInv32 polynomial (math.cc), no fp contraction to match XLA rounding.
__device__ float xla_erfinv(float x) {
#pragma clang fp contract(off)
  float w = -log1pf(-x * x);
  float p;
  if (w < 5.0f) {
    w = w - 2.5f;
    p = 2.81022636e-08f;
    p = 3.43273939e-07f  + p * w;
    p = -3.5233877e-06f  + p * w;
    p = -4.39150654e-06f + p * w;
    p = 0.00021858087f   + p * w;
    p = -0.00125372503f  + p * w;
    p = -0.00417768164f  + p * w;
    p = 0.246640727f     + p * w;
    p = 1.50140941f      + p * w;
  } else {
    w = sqrtf(w) - 3.0f;
    p = -0.000200214257f;
    p = 0.000100950558f + p * w;
    p = 0.00134934322f  + p * w;
    p = -0.00367342844f + p * w;
    p = 0.00573950773f  + p * w;
    p = -0.0076224613f  + p * w;
    p = 0.00943887047f  + p * w;
    p = 1.00167406f     + p * w;
    p = 2.83297682f     + p * w;
  }
  return p * x;
}

// rot element for flat RNG index i (rot shape (16,4,64) row-major).
__device__ float rot_rng(int i) {
  unsigned o0, o1, bits;
#if JAX_THREEFRY_PARTITIONABLE
  tf2x32(0u, 42u, 0u, (unsigned)i, o0, o1);
  bits = o0 ^ o1;
#else
  if (i < 2048) { tf2x32(0u, 42u, (unsigned)i, (unsigned)(i + 2048), o0, o1); bits = o0; }
  else          { tf2x32(0u, 42u, (unsigned)(i - 2048), (unsigned)i, o0, o1); bits = o1; }
#endif
  unsigned fb = (bits >> 9) | 0x3f800000u;
  float f = __uint_as_float(fb) - 1.0f;
  const float lo = __uint_as_float(0xBF7FFFFFu);  // nextafter(-1,0)
  float u = fmaxf(lo, f * 2.0f + lo);
  return __uint_as_float(0x3FB504F3u) * xla_erfinv(u);  // sqrt(2)*erfinv(u)
}

// conv1 (m-block, 64->16 3x3), K-split in 4 quarters of 16 ci; inline weight
// transpose from raw mw1 (L2-cached). 512 threads = (co, xq, yl); 4 px/thread.
__global__ __launch_bounds__(512) void k_conv1(
    const float* __restrict__ fd1, const float* __restrict__ fd2,
    const float* __restrict__ mw1,
    float* __restrict__ ht0, float* __restrict__ ht1,
    float* __restrict__ ht2, float* __restrict__ ht3) {
  // grid = 1456 = 8*182 exactly; XCD swizzle keeps kq-siblings on one XCD L2.
  int x = blockIdx.x;
  int blk = (x & 7) * 182 + (x >> 3);
  int kq = blk & 3;
  int rest = blk >> 2;                   // 0..363 = img n (0..3) x 91 tiles
  int n = rest / 91, tile = rest % 91;
  int yt = tile / 7, xt = tile % 7;      // 13 y-tiles x 7 x-tiles
  int ty0 = yt * 8, tx0 = xt * 16;
  const float* in = ((n >> 1) ? fd2 : fd1) + (n & 1) * (C0 * LL) + (kq * 16) * LL;
  float* htk = ((kq == 0) ? ht0 : (kq == 1) ? ht1 : (kq == 2) ? ht2 : ht3) + n * 16 * LL;
  int tid = threadIdx.x;
  int co = tid & 15, xq = (tid >> 4) & 3, yl = tid >> 6;   // yl 0..7

  __shared__ float sIn[16 * 10 * 20];   // [ci][10 rows][20 pad (18 used)]
  __shared__ float sW[144 * 16];        // [(ci*9+t)][co], transposed inline

  for (int i = tid; i < 144 * 16; i += 512) {
    int o = i & 15, r = i >> 4;
    sW[i] = mw1[o * 576 + kq * 144 + r];
  }
  for (int idx = tid; idx < 16 * 10 * 18; idx += 512) {
    int ci = idx / 180, r = idx % 180, iy = r / 18, ix = r % 18;
    int gy = ty0 - 1 + iy, gx = tx0 - 1 + ix;
    float v = 0.f;
    if (gy >= 0 && gy < HH && gx >= 0 && gx < WWW) v = in[ci * LL + gy * WWW + gx];
    sIn[ci * 200 + iy * 20 + ix] = v;
  }
  __syncthreads();

  float acc[4];
#pragma unroll
  for (int p = 0; p < 4; ++p) acc[p] = 0.f;

  for (int cc = 0; cc < 4; ++cc) {   // 4-ci chunks
    float w[4][9];
#pragma unroll
    for (int c4 = 0; c4 < 4; ++c4)
#pragma unroll
      for (int t = 0; t < 9; ++t)
        w[c4][t] = sW[((cc * 4 + c4) * 9 + t) * 16 + co];
#pragma unroll
    for (int c4 = 0; c4 < 4; ++c4) {
      const float* rowb = &sIn[(cc * 4 + c4) * 200 + yl * 20 + xq * 4];
#pragma unroll
      for (int dy = 0; dy < 3; ++dy) {
        const float* r = rowb + dy * 20;
        float v[6];
#pragma unroll
        for (int k = 0; k < 6; ++k) v[k] = r[k];
#pragma unroll
        for (int dx = 0; dx < 3; ++dx) {
          float wv = w[c4][dy * 3 + dx];
#pragma unroll
          for (int p = 0; p < 4; ++p) acc[p] = fmaf(v[p + dx], wv, acc[p]);
        }
      }
    }
  }

  int yv = ty0 + yl;
  int xg = tx0 + xq * 4;
  if (yv < HH && xg < WWW) {   // xg multiple of 4; 100 % 4 == 0, no straddle
    float4 s = make_float4(acc[0], acc[1], acc[2], acc[3]);
    *(float4*)&htk[co * LL + yv * WWW + xg] = s;
  }
}

// conv2 (16->16 3x3 + b2) + skip (1x1 64->16 + mbs), h = relu(sum ht + mb1)
// fused into halo staging; inline weight transposes from raw mw2/mws.
__global__ __launch_bounds__(512) void k_conv2(
    const float* __restrict__ fd1, const float* __restrict__ fd2,
    const float* __restrict__ ht0, const float* __restrict__ ht1,
    const float* __restrict__ ht2, const float* __restrict__ ht3,
    const float* __restrict__ mw2, const float* __restrict__ mb1,
    const float* __restrict__ mb2, const float* __restrict__ mws,
    const float* __restrict__ mbs, float* __restrict__ F) {
  // XCD swizzle for 364 blocks: bijective 46/45 chunking (364 = 4*46 + 4*45).
  int xx = blockIdx.x;
  int xcd = xx & 7, slot = xx >> 3;
  int blk = (xcd < 4) ? (xcd * 46 + slot) : (184 + (xcd - 4) * 45 + slot);
  int n = blk / 91, tile = blk % 91;
  int yt = tile / 7, xt = tile % 7;       // 13 y-tiles x 7 x-tiles
  int ty0 = yt * 8, tx0 = xt * 16;
  int src = n >> 1, b = n & 1;
  const float* in = (src ? fd2 : fd1) + b * (C0 * LL);
  const float* h0 = ht0 + n * 16 * LL;
  const float* h1 = ht1 + n * 16 * LL;
  const float* h2 = ht2 + n * 16 * LL;
  const float* h3 = ht3 + n * 16 * LL;
  int tid = threadIdx.x;
  int co = tid & 15, xq = (tid >> 4) & 3, yl = tid >> 6;   // yl 0..7

  __shared__ float sW2[144 * 16];         // [(ci*9+t)][co]
  __shared__ float sWs[64 * 16];          // [ci][co]
  __shared__ float sH[16 * 10 * 20];      // h halo [ci][10 rows][20 pad (18 used)]
  __shared__ float sSkip[16 * 8 * 17];    // skip chunk [ci16][8][17 pad (16 used)]

  for (int i = tid; i < 144 * 16; i += 512) {
    int o = i & 15, r = i >> 4;
    sW2[i] = mw2[o * 144 + r];
  }
  for (int i = tid; i < 64 * 16; i += 512) {
    int o = i & 15, ci = i >> 4;
    sWs[i] = mws[o * 64 + ci];
  }
  for (int idx = tid; idx < 16 * 10 * 18; idx += 512) {
    int ci = idx / 180, r = idx % 180, iy = r / 18, ix = r % 18;
    int gy = ty0 - 1 + iy, gx = tx0 - 1 + ix;
    float v = 0.f;
    if (gy >= 0 && gy < HH && gx >= 0 && gx < WWW) {
      int o = ci * LL + gy * WWW + gx;
      v = fmaxf(h0[o] + h1[o] + h2[o] + h3[o] + mb1[ci], 0.f);
    }
    sH[ci * 200 + iy * 20 + ix] = v;
  }
  __syncthreads();

  float acc[4];
  float bias = mb2[co] + mbs[co];
#pragma unroll
  for (int p = 0; p < 4; ++p) acc[p] = bias;

  // conv 3x3 over the 16 h-channels
  for (int ci = 0; ci < 16; ++ci) {
    const float* rowb = &sH[ci * 200 + yl * 20 + xq * 4];
#pragma unroll
    for (int dy = 0; dy < 3; ++dy) {
      const float* r = rowb + dy * 20;
      float v[6];
#pragma unroll
      for (int k = 0; k < 6; ++k) v[k] = r[k];
#pragma unroll
      for (int dx = 0; dx < 3; ++dx) {
        float wv = sW2[(ci * 9 + dy * 3 + dx) * 16 + co];
#pragma unroll
        for (int p = 0; p < 4; ++p) acc[p] = fmaf(v[p + dx], wv, acc[p]);
      }
    }
  }

  // skip 1x1 over 64 ci, staged in 4 chunks of 16 ci
  for (int cc = 0; cc < 4; ++cc) {
    __syncthreads();
    for (int idx = tid; idx < 16 * 8 * 16; idx += 512) {
      int ci = idx >> 7, r = idx & 127, iy = r >> 4, ix = r & 15;
      int gy = ty0 + iy, gx = tx0 + ix;
      float v = 0.f;
      if (gy < HH && gx < WWW) v = in[(cc * 16 + ci) * LL + gy * WWW + gx];
      sSkip[(ci * 8 + iy) * 17 + ix] = v;
    }
    __syncthreads();
    for (int c16 = 0; c16 < 16; ++c16) {
      float wv = sWs[(cc * 16 + c16) * 16 + co];
      const float* sv = &sSkip[(c16 * 8 + yl) * 17 + xq * 4];
#pragma unroll
      for (int p = 0; p < 4; ++p) acc[p] = fmaf(sv[p], wv, acc[p]);
    }
  }

  int yv = ty0 + yl;
  if (yv < HH) {
    float* Fb = F + (b * TL + src * LL + yv * WWW) * 16 + co;
#pragma unroll
    for (int p = 0; p < 4; ++p) {
      int xv = tx0 + xq * 4 + p;
      if (xv < WWW) Fb[xv * 16] = acc[p];
    }
  }
}

// Flat 320-block kernel, 576 threads:
//  blocks 0..279   : codes (35 segs x 8 bh); rot computed inline via threefry
//  blocks 280..283 : rA/rB point-resblock (raw aux weights, transposed reads)
//  block  284      : per-batch E scalars
//  blocks 285..319 : inv permutation scatter
__global__ __launch_bounds__(576) void k_codes(
    const float* __restrict__ F, const int* __restrict__ ri,
    unsigned char* __restrict__ codes,
    const float* __restrict__ fd1, const float* __restrict__ refin,
    const float* __restrict__ a1w1, const float* __restrict__ a1b1,
    const float* __restrict__ a1w2, const float* __restrict__ a1b2,
    const float* __restrict__ a2w1, const float* __restrict__ a2b1,
    const float* __restrict__ a2w2, const float* __restrict__ a2b2,
    float* __restrict__ SC, int* __restrict__ inv) {
  int blk = blockIdx.x;
  int tid = threadIdx.x;

  if (blk < 280) {
    int bh = blk / 35, seg = blk % 35;
    int b = bh >> 2, h = bh & 3;
    __shared__ float srot[1024];   // [j][c], j 0..63, c 0..15
    for (int l = tid; l < 1024; l += 576) {
      int j = l >> 4, c = l & 15;
      srot[l] = rot_rng(c * 256 + h * 64 + j);
    }
    __syncthreads();
    int t = seg * 576 + tid;
    if (t >= TL) return;
    int pos = ri[t];
    const float* Fr = F + (b * TL + pos) * 16;
    float q[16];
#pragma unroll
    for (int c = 0; c < 16; ++c) q[c] = Fr[c];
    float best = -1e30f; int bi = 0;
    float worst = 1e30f; int wi = 0;
    for (int j = 0; j < 64; ++j) {
      float v = 0.f;
      const float* rp = srot + j * 16;
#pragma unroll
      for (int c = 0; c < 16; ++c) v = fmaf(q[c], rp[c], v);
      if (v > best)  { best = v;  bi = j; }
      if (v < worst) { worst = v; wi = j; }
    }
    int code = (best >= -worst) ? bi : (64 + wi);
    codes[bh * TL + t] = (unsigned char)code;
    return;
  }

  if (blk >= 285) {   // inv scatter
    int t = (blk - 285) * 576 + tid;
    if (t < TL) {
      int p = ri[t];
      if (p < LL) inv[p] = t;
    }
    return;
  }

  if (blk == 284) {
#pragma clang fp contract(off)
    int b = tid;
    if (b >= BN) return;
    int j0 = ri[0], jL = ri[LL];
    const float* qA = F + (b * TL + j0) * 16;
    const float* qB = F + (b * TL + jL) * 16;
    float nA = 0.f, nB = 0.f;
    for (int c = 0; c < 16; ++c) { nA += qA[c] * qA[c]; nB += qB[c] * qB[c]; }
    float mA = fmaxf(sqrtf(nA), 5e-5f), mB = fmaxf(sqrtf(nB), 5e-5f);
    float d00 = 0.f, d01 = 0.f, d10 = 0.f, d11 = 0.f;
    for (int c = 0; c < 16; ++c) {
      float kAc = qA[c] / mA, kBc = qB[c] / mB;
      d00 += qA[c] * kAc; d01 += qA[c] * kBc;
      d10 += qB[c] * kAc; d11 += qB[c] * kBc;
    }
    float zA = (j0 < LL) ? 0.01f : 0.99f;
    float zB = (jL < LL) ? 0.01f : 0.99f;
    float* sc = SC + b * 136;
    sc[0] = expf(d00) * zA; sc[1] = expf(d01) * zB;
    sc[2] = expf(d10) * zA; sc[3] = expf(d11) * zB;
    return;
  }

  // point-resblock path (blocks 280..283)
  int pb = blk - 280;
  int b = pb & 1, which = pb >> 1;
  int pos = ri[which * LL];
  const float *in, *w1, *b1, *w2, *b2;
  int sp;
  if (pos < LL) {
    in = fd1 + b * C0 * LL; w1 = a1w1; b1 = a1b1; w2 = a1w2; b2 = a1b2; sp = pos;
  } else {
    in = refin + b * C0 * LL; w1 = a2w1; b1 = a2b1; w2 = a2w2; b2 = a2b2;
    sp = pos - LL;
  }
  int y = sp / WWW, x = sp % WWW;

  __shared__ float sPatch[64][25];
  __shared__ float sW[144 * 64];
  __shared__ float sH[9][64];
  __shared__ float sPart[9][64];

  for (int idx = tid; idx < 64 * 25; idx += 576) {
    int ci = idx / 25, pp = idx % 25;
    int gy = y - 2 + pp / 5, gx = x - 2 + pp % 5;
    float v = 0.f;
    if (gy >= 0 && gy < HH && gx >= 0 && gx < WWW) v = in[ci * LL + gy * WWW + gx];
    sPatch[ci][pp] = v;
  }

  int p = tid / 64, ch = tid & 63;
  int p3 = p / 3, pm = p % 3;
  int yy = y + p3 - 1, xx = x + pm - 1;
  bool inb = (yy >= 0) && (yy < HH) && (xx >= 0) && (xx < WWW);

  float acc0 = 0.f, acc1 = 0.f;
  for (int cc = 0; cc < 4; ++cc) {
    __syncthreads();
    for (int i = tid; i < 144 * 64; i += 576) {
      int chh = i & 63, rl = i >> 6;
      sW[i] = w1[chh * 576 + cc * 144 + rl];   // transposed read of raw weights
    }
    __syncthreads();
    if (inb) {
#pragma unroll
      for (int ci = 0; ci < 16; ++ci) {
        const float* wp = &sW[ci * 9 * 64 + ch];
        const float* pr = &sPatch[cc * 16 + ci][0];
#pragma unroll
        for (int t = 0; t < 9; ++t) {
          float v = pr[(p3 + t / 3) * 5 + (pm + t % 3)];
          if (ci & 1) acc1 = fmaf(v, wp[t * 64], acc1);
          else        acc0 = fmaf(v, wp[t * 64], acc0);
        }
      }
    }
  }
  sH[p][ch] = inb ? fmaxf(acc0 + acc1 + b1[ch], 0.f) : 0.f;
  __syncthreads();

  {
    float part = 0.f;
    for (int ci = 0; ci < 64; ++ci)
      part = fmaf(sH[p][ci], w2[ch * 576 + ci * 9 + p], part);
    sPart[p][ch] = part;
  }
  __syncthreads();
  if (tid < 64) {
    int co = tid;
    float a = in[co * LL + y * WWW + x] + b2[co];
#pragma unroll
    for (int g = 0; g < 9; ++g) a += sPart[g][co];
    SC[b * 136 + 4 + which * 64 + co] = a;
  }
}

// stable counting sort per (b,h); hierarchical prefix (supergroups of 16) to
// avoid 240-long serial LDS chains; keys register-cached.
__global__ __launch_bounds__(256) void k_sort(
    const unsigned char* __restrict__ codes,
    int* __restrict__ rank_of, int* __restrict__ n0g) {
  int bh = blockIdx.x;
  const unsigned int* keys4 = (const unsigned int*)(codes + bh * TL);
  __shared__ unsigned short cnt[128 * 241];   // [class][group], pad 241
  __shared__ unsigned int sup[128 * 16];      // per-class supergroup partial/scan
  __shared__ unsigned int totalsL[128];
  __shared__ unsigned int baseoff[128];
  __shared__ unsigned int n0s[NCHK];
  __shared__ unsigned int wtot;
  int tid = threadIdx.x;

  for (int i = tid; i < 128 * 241 / 2; i += 256) ((unsigned int*)cnt)[i] = 0u;
  for (int i = tid; i < NCHK; i += 256) n0s[i] = 0u;
  __syncthreads();

  const int SEG = 84;   // 238 full groups + group 238 has 8 elems (239 groups used)
  int base = tid * SEG;
  int nloc = (tid < 240) ? (TL - base) : 0;
  if (nloc > SEG) nloc = SEG;
  if (nloc < 0) nloc = 0;

  // load keys once into registers (u32 words; base is 4B aligned)
  unsigned int kw[21];
  int nw = (nloc + 3) >> 2;
  for (int w = 0; w < nw; ++w) kw[w] = keys4[tid * 21 + w];

  // Phase 1: count
  for (int e = 0; e < nloc; ++e) {
    int c = (kw[e >> 2] >> ((e & 3) * 8)) & 255;
    cnt[c * 241 + tid]++;
  }
  __syncthreads();

  // Phase 2a: supergroup partial sums (15 supergroups of 16 groups)
  for (int idx = tid; idx < 128 * 15; idx += 256) {
    int c = idx / 15, s = idx % 15;
    unsigned int sum = 0;
#pragma unroll
    for (int k = 0; k < 16; ++k) sum += cnt[c * 241 + 16 * s + k];
    sup[c * 16 + s] = sum;
  }
  __syncthreads();

  // Phase 2b: exclusive scan over supergroups per class (15-long, 128 parallel)
  if (tid < 128) {
    unsigned int run = 0;
#pragma unroll
    for (int s = 0; s < 15; ++s) {
      unsigned int t = sup[tid * 16 + s];
      sup[tid * 16 + s] = run;
      run += t;
    }
    totalsL[tid] = run;
  }
  __syncthreads();

  // Phase 2c: baseoff = exclusive scan of totals over classes (wave shfl scan)
  {
    unsigned int v = 0;
    if (tid < 128) {
      v = totalsL[tid];
#pragma unroll
      for (int d = 1; d < 64; d <<= 1) {
        unsigned int o = __shfl_up(v, d);
        if ((tid & 63) >= d) v += o;
      }
      if (tid == 63) wtot = v;
    }
    __syncthreads();
    if (tid < 128) {
      unsigned int incl = v + ((tid >= 64) ? wtot : 0u);
      baseoff[tid] = incl - totalsL[tid];
    }
  }
  __syncthreads();

  // Phase 3: final per-group offsets written back into cnt (16-long chains,
  // 1920 independent tasks interleaved over 256 threads)
  for (int idx = tid; idx < 128 * 15; idx += 256) {
    int c = idx / 15, s = idx % 15;
    unsigned int run = baseoff[c] + sup[c * 16 + s];
#pragma unroll
    for (int k = 0; k < 16; ++k) {
      int g = 16 * s + k;
      unsigned int t = cnt[c * 241 + g];
      cnt[c * 241 + g] = (unsigned short)run;
      run += t;
    }
  }
  __syncthreads();

  // Phase 4: placement (stable within segment), n0 histogram
  for (int e = 0; e < nloc; ++e) {
    int idx = base + e;
    int c = (kw[e >> 2] >> ((e & 3) * 8)) & 255;
    unsigned int r = cnt[c * 241 + tid]++;
    rank_of[bh * TL + idx] = (int)r;
    if (!(idx & 1)) {
      atomicAdd(&n0s[r / CHK], 1u);
      if (r >= TL - NPAD) atomicAdd(&n0s[NCHK - 1], 1u);
    }
  }
  __syncthreads();
  for (int i = tid; i < NCHK; i += 256) n0g[bh * NCHK + i] = (int)n0s[i];
}

// out[b][c][p]: t = inv[p]; alpha/beta computed inline from rank_of/n0.
// c-split 4 ways (blockIdx.z) for occupancy on this gather-latency-bound kernel.
__global__ __launch_bounds__(256) void k_out(
    const int* __restrict__ inv, const int* __restrict__ rank_of,
    const int* __restrict__ n0, const float* __restrict__ SC,
    float* __restrict__ out) {
  int b = blockIdx.y;
  int c0 = blockIdx.z * 16;
  int p = blockIdx.x * 256 + threadIdx.x;
  if (p >= LL) return;
  int t = inv[p];
  int si = t & 1;
  float e0 = SC[b * 136 + si * 2 + 0];
  float e1 = SC[b * 136 + si * 2 + 1];
  float s0 = 0.f, s1 = 0.f;
  for (int h = 0; h < 4; ++h) {
    int r = rank_of[(b * 4 + h) * TL + t];
    int k = r / CHK;
    int km = (k == 0) ? NCHK - 1 : k - 1;
    int kp = (k == NCHK - 1) ? 0 : k + 1;
    const int* nb = n0 + (b * 4 + h) * NCHK;
    int W0 = nb[k] + nb[km] + nb[kp];
    s0 += (float)W0 * e0;
    s1 += (float)(WINR - W0) * e1;
  }
  float invd = 1.f / (s0 + s1);
  float al = s0 * invd;
  float be = s1 * invd;
  const float* rA = SC + b * 136 + 4;
  const float* rB = rA + 64;
  float* o = out + b * C0 * LL + p;
#pragma unroll
  for (int c = 0; c < 16; ++c) o[(c0 + c) * LL] = al * rA[c0 + c] + be * rB[c0 + c];
}

}  // namespace

extern "C" void kernel_launch(void* const* d_in, const int* in_sizes, int n_in,
                              void* d_out, int out_size, void* d_ws, size_t ws_size,
                              hipStream_t stream) {
  const float* fd1  = (const float*)d_in[0];
  const float* fd2  = (const float*)d_in[1];
  const float* reff = (const float*)d_in[2];
  const int*   ri   = (const int*)d_in[3];
  const float* mw1  = (const float*)d_in[4];
  const float* mb1  = (const float*)d_in[5];
  const float* mw2  = (const float*)d_in[6];
  const float* mb2  = (const float*)d_in[7];
  const float* mws  = (const float*)d_in[8];
  const float* mbs  = (const float*)d_in[9];
  const float* a1w1 = (const float*)d_in[10];
  const float* a1b1 = (const float*)d_in[11];
  const float* a1w2 = (const float*)d_in[12];
  const float* a1b2 = (const float*)d_in[13];
  const float* a2w1 = (const float*)d_in[14];
  const float* a2b1 = (const float*)d_in[15];
  const float* a2w2 = (const float*)d_in[16];
  const float* a2b2 = (const float*)d_in[17];

  float* ws = (float*)d_ws;
  float* ht0  = ws + OFF_HT0;
  float* ht1  = ws + OFF_HT1;
  float* ht2  = ws + OFF_HT2;
  float* ht3  = ws + OFF_HT3;
  float* F    = ws + OFF_F;
  float* SC   = ws + OFF_SC;
  unsigned char* codes = (unsigned char*)(ws + OFF_CODE);
  int* rank_of = (int*)(ws + OFF_RANK);
  int* n0      = (int*)(ws + OFF_N0);
  int* invp    = (int*)(ws + OFF_INV);

  k_conv1<<<dim3(1456), dim3(512), 0, stream>>>(fd1, fd2, mw1, ht0, ht1, ht2, ht3);
  k_conv2<<<dim3(364), dim3(512), 0, stream>>>(fd1, fd2, ht0, ht1, ht2, ht3, mw2,
                                               mb1, mb2, mws, mbs, F);
  k_codes<<<dim3(320), dim3(576), 0, stream>>>(F, ri, codes, fd1, reff,
                                               a1w1, a1b1, a1w2, a1b2,
                                               a2w1, a2b1, a2w2, a2b2, SC, invp);
  k_sort<<<dim3(8), dim3(256), 0, stream>>>(codes, rank_of, n0);
  k_out<<<dim3(40, 2, 4), dim3(256), 0, stream>>>(invp, rank_of, n0, SC, (float*)d_out);
}

// Round 10
// 122.429 us; speedup vs baseline: 1.1388x; 1.1388x over previous
//
#include <hip/hip_runtime.h>

// Flip to 0 if absmax fails large: selects legacy (non-partitionable) JAX threefry stream.
#define JAX_THREEFRY_PARTITIONABLE 1

namespace {

constexpr int BN   = 2;      // batch
constexpr int C0   = 64;
constexpr int HH   = 100;
constexpr int WWW  = 100;
constexpr int LL   = 10000;  // H*W
constexpr int TL   = 20000;  // 2L
constexpr int CHK  = 144;
constexpr int NCHK = 139;    // (TL+16)/144
constexpr int NPAD = 16;
constexpr int WINR = 432;    // 3*144

// ws layout in float slots
constexpr int OFF_HT0  = 0;                    // conv1 partial kq=0 [4][16][10000]
constexpr int OFF_HT1  = OFF_HT0 + 640000;     // kq=1
constexpr int OFF_HT2  = OFF_HT1 + 640000;     // kq=2
constexpr int OFF_HT3  = OFF_HT2 + 640000;     // kq=3
constexpr int OFF_F    = OFF_HT3 + 640000;     // F [2][20000][16]
constexpr int OFF_SC   = OFF_F + 640000;       // SC [2][136]
constexpr int OFF_CODE = OFF_SC + 272;         // codes u8 [8][20000]
constexpr int OFF_RANK = OFF_CODE + 40000;     // rank int [8][20000]
constexpr int OFF_N0   = OFF_RANK + 160000;    // n0 int [8][139]
constexpr int OFF_INV  = OFF_N0 + 1112;        // inv int [10000]
constexpr int OFF_AUX  = OFF_INV + 10000;      // auxT: 4 x [576][64]
constexpr int OFF_ROT  = OFF_AUX + 147456;     // rotT [4][64][16]

constexpr int AUXW = 36864;  // 64*64*9

__device__ __forceinline__ unsigned rotl32(unsigned v, int r) {
  return (v << r) | (v >> (32 - r));
}

// JAX threefry2x32, 20 rounds, key injection every 4.
__device__ void tf2x32(unsigned k0, unsigned k1, unsigned x0, unsigned x1,
                       unsigned& o0, unsigned& o1) {
  unsigned ks2 = k0 ^ k1 ^ 0x1BD11BDAu;
  x0 += k0; x1 += k1;
#define TFR(r) { x0 += x1; x1 = rotl32(x1, r); x1 ^= x0; }
  TFR(13) TFR(15) TFR(26) TFR(6)  x0 += k1;  x1 += ks2 + 1u;
  TFR(17) TFR(29) TFR(16) TFR(24) x0 += ks2; x1 += k0 + 2u;
  TFR(13) TFR(15) TFR(26) TFR(6)  x0 += k0;  x1 += k1 + 3u;
  TFR(17) TFR(29) TFR(16) TFR(24) x0 += k1;  x1 += ks2 + 4u;
  TFR(13) TFR(15) TFR(26) TFR(6)  x0 += ks2; x1 += k0 + 5u;
#undef TFR
  o0 = x0; o1 = x1;
}

// XLA's ErfInv32 polynomial (math.cc), no fp contraction to match XLA rounding.
__device__ float xla_erfinv(float x) {
#pragma clang fp contract(off)
  float w = -log1pf(-x * x);
  float p;
  if (w < 5.0f) {
    w = w - 2.5f;
    p = 2.81022636e-08f;
    p = 3.43273939e-07f  + p * w;
    p = -3.5233877e-06f  + p * w;
    p = -4.39150654e-06f + p * w;
    p = 0.00021858087f   + p * w;
    p = -0.00125372503f  + p * w;
    p = -0.00417768164f  + p * w;
    p = 0.246640727f     + p * w;
    p = 1.50140941f      + p * w;
  } else {
    w = sqrtf(w) - 3.0f;
    p = -0.000200214257f;
    p = 0.000100950558f + p * w;
    p = 0.00134934322f  + p * w;
    p = -0.00367342844f + p * w;
    p = 0.00573950773f  + p * w;
    p = -0.0076224613f  + p * w;
    p = 0.00943887047f  + p * w;
    p = 1.00167406f     + p * w;
    p = 2.83297682f     + p * w;
  }
  return p * x;
}

// rot element for flat RNG index i (rot shape (16,4,64) row-major).
__device__ float rot_rng(int i) {
  unsigned o0, o1, bits;
#if JAX_THREEFRY_PARTITIONABLE
  tf2x32(0u, 42u, 0u, (unsigned)i, o0, o1);
  bits = o0 ^ o1;
#else
  if (i < 2048) { tf2x32(0u, 42u, (unsigned)i, (unsigned)(i + 2048), o0, o1); bits = o0; }
  else          { tf2x32(0u, 42u, (unsigned)(i - 2048), (unsigned)i, o0, o1); bits = o1; }
#endif
  unsigned fb = (bits >> 9) | 0x3f800000u;
  float f = __uint_as_float(fb) - 1.0f;
  const float lo = __uint_as_float(0xBF7FFFFFu);  // nextafter(-1,0)
  float u = fmaxf(lo, f * 2.0f + lo);
  return __uint_as_float(0x3FB504F3u) * xla_erfinv(u);  // sqrt(2)*erfinv(u)
}

// conv1 (m-block, 64->16 3x3), K-split in 4 quarters of 16 ci.
// Blocks 0..1455: conv tiles (XCD-swizzled). Blocks 1456..1751: auxT transpose
// + rotT RNG prep (consumed by the later k_codes kernel; stream-ordered).
__global__ __launch_bounds__(512) void k_conv1(
    const float* __restrict__ fd1, const float* __restrict__ fd2,
    const float* __restrict__ mw1,
    const float* __restrict__ a1w1, const float* __restrict__ a1w2,
    const float* __restrict__ a2w1, const float* __restrict__ a2w2,
    float* __restrict__ ht0, float* __restrict__ ht1,
    float* __restrict__ ht2, float* __restrict__ ht3,
    float* __restrict__ auxT, float* __restrict__ rotT) {
  int x = blockIdx.x;
  int tid = threadIdx.x;
  if (x >= 1456) {   // prep blocks: 296 x 512 = 151552 = 147456 aux + 4096 rot
    int idx = (x - 1456) * 512 + tid;
    if (idx < 4 * AUXW) {
      int wsel = idx / AUXW, j = idx % AUXW;
      const float* src = (wsel == 0) ? a1w1 : (wsel == 1) ? a1w2
                       : (wsel == 2) ? a2w1 : a2w2;
      int co = j / 576, r = j % 576;           // coalesced read in j
      auxT[wsel * AUXW + r * 64 + co] = src[j];
    } else {
      int i = idx - 4 * AUXW;                  // 0..4095
      float rv = rot_rng(i);
      int c = i >> 8, h = (i >> 6) & 3, jj = i & 63;
      rotT[(h * 64 + jj) * 16 + c] = rv;
    }
    return;
  }
  // grid portion 1456 = 8*182 exactly; XCD swizzle keeps kq-siblings together.
  int blk = (x & 7) * 182 + (x >> 3);
  int kq = blk & 3;
  int rest = blk >> 2;                   // 0..363 = img n (0..3) x 91 tiles
  int n = rest / 91, tile = rest % 91;
  int yt = tile / 7, xt = tile % 7;      // 13 y-tiles x 7 x-tiles
  int ty0 = yt * 8, tx0 = xt * 16;
  const float* in = ((n >> 1) ? fd2 : fd1) + (n & 1) * (C0 * LL) + (kq * 16) * LL;
  float* htk = ((kq == 0) ? ht0 : (kq == 1) ? ht1 : (kq == 2) ? ht2 : ht3) + n * 16 * LL;
  int co = tid & 15, xq = (tid >> 4) & 3, yl = tid >> 6;   // yl 0..7

  __shared__ float sIn[16 * 10 * 20];   // [ci][10 rows][20 pad (18 used)]
  __shared__ float sW[144 * 17];        // [(ci*9+t)][co], row pad 17

  // coalesced read (r fastest), transposed conflict-free LDS write (stride 17)
  for (int i = tid; i < 2304; i += 512) {
    int o = i / 144, r = i % 144;
    sW[r * 17 + o] = mw1[o * 576 + kq * 144 + r];
  }
  for (int idx = tid; idx < 16 * 10 * 18; idx += 512) {
    int ci = idx / 180, r = idx % 180, iy = r / 18, ix = r % 18;
    int gy = ty0 - 1 + iy, gx = tx0 - 1 + ix;
    float v = 0.f;
    if (gy >= 0 && gy < HH && gx >= 0 && gx < WWW) v = in[ci * LL + gy * WWW + gx];
    sIn[ci * 200 + iy * 20 + ix] = v;
  }
  __syncthreads();

  float acc[4];
#pragma unroll
  for (int p = 0; p < 4; ++p) acc[p] = 0.f;

  for (int cc = 0; cc < 4; ++cc) {   // 4-ci chunks
    float w[4][9];
#pragma unroll
    for (int c4 = 0; c4 < 4; ++c4)
#pragma unroll
      for (int t = 0; t < 9; ++t)
        w[c4][t] = sW[((cc * 4 + c4) * 9 + t) * 17 + co];
#pragma unroll
    for (int c4 = 0; c4 < 4; ++c4) {
      const float* rowb = &sIn[(cc * 4 + c4) * 200 + yl * 20 + xq * 4];
#pragma unroll
      for (int dy = 0; dy < 3; ++dy) {
        const float* r = rowb + dy * 20;
        float v[6];
#pragma unroll
        for (int k = 0; k < 6; ++k) v[k] = r[k];
#pragma unroll
        for (int dx = 0; dx < 3; ++dx) {
          float wv = w[c4][dy * 3 + dx];
#pragma unroll
          for (int p = 0; p < 4; ++p) acc[p] = fmaf(v[p + dx], wv, acc[p]);
        }
      }
    }
  }

  int yv = ty0 + yl;
  int xg = tx0 + xq * 4;
  if (yv < HH && xg < WWW) {   // xg multiple of 4; 100 % 4 == 0, no straddle
    float4 s = make_float4(acc[0], acc[1], acc[2], acc[3]);
    *(float4*)&htk[co * LL + yv * WWW + xg] = s;
  }
}

// conv2 (16->16 3x3 + b2) + skip (1x1 64->16 + mbs), h = relu(sum ht + mb1)
// fused into halo staging; coalesced-read/transposed-write weight staging.
__global__ __launch_bounds__(512) void k_conv2(
    const float* __restrict__ fd1, const float* __restrict__ fd2,
    const float* __restrict__ ht0, const float* __restrict__ ht1,
    const float* __restrict__ ht2, const float* __restrict__ ht3,
    const float* __restrict__ mw2, const float* __restrict__ mb1,
    const float* __restrict__ mb2, const float* __restrict__ mws,
    const float* __restrict__ mbs, float* __restrict__ F) {
  // XCD swizzle for 364 blocks: bijective 46/45 chunking (364 = 4*46 + 4*45).
  int xx = blockIdx.x;
  int xcd = xx & 7, slot = xx >> 3;
  int blk = (xcd < 4) ? (xcd * 46 + slot) : (184 + (xcd - 4) * 45 + slot);
  int n = blk / 91, tile = blk % 91;
  int yt = tile / 7, xt = tile % 7;       // 13 y-tiles x 7 x-tiles
  int ty0 = yt * 8, tx0 = xt * 16;
  int src = n >> 1, b = n & 1;
  const float* in = (src ? fd2 : fd1) + b * (C0 * LL);
  const float* h0 = ht0 + n * 16 * LL;
  const float* h1 = ht1 + n * 16 * LL;
  const float* h2 = ht2 + n * 16 * LL;
  const float* h3 = ht3 + n * 16 * LL;
  int tid = threadIdx.x;
  int co = tid & 15, xq = (tid >> 4) & 3, yl = tid >> 6;   // yl 0..7

  __shared__ float sW2[144 * 17];         // [(ci*9+t)][co], pad 17
  __shared__ float sWs[64 * 17];          // [ci][co], pad 17
  __shared__ float sH[16 * 10 * 20];      // h halo [ci][10 rows][20 pad (18 used)]
  __shared__ float sSkip[16 * 8 * 17];    // skip chunk [ci16][8][17 pad (16 used)]

  for (int i = tid; i < 2304; i += 512) {
    int o = i / 144, r = i % 144;
    sW2[r * 17 + o] = mw2[o * 144 + r];
  }
  for (int i = tid; i < 1024; i += 512) {
    int o = i / 64, ci = i % 64;
    sWs[ci * 17 + o] = mws[o * 64 + ci];
  }
  for (int idx = tid; idx < 16 * 10 * 18; idx += 512) {
    int ci = idx / 180, r = idx % 180, iy = r / 18, ix = r % 18;
    int gy = ty0 - 1 + iy, gx = tx0 - 1 + ix;
    float v = 0.f;
    if (gy >= 0 && gy < HH && gx >= 0 && gx < WWW) {
      int o = ci * LL + gy * WWW + gx;
      v = fmaxf(h0[o] + h1[o] + h2[o] + h3[o] + mb1[ci], 0.f);
    }
    sH[ci * 200 + iy * 20 + ix] = v;
  }
  __syncthreads();

  float acc[4];
  float bias = mb2[co] + mbs[co];
#pragma unroll
  for (int p = 0; p < 4; ++p) acc[p] = bias;

  // conv 3x3 over the 16 h-channels
  for (int ci = 0; ci < 16; ++ci) {
    const float* rowb = &sH[ci * 200 + yl * 20 + xq * 4];
#pragma unroll
    for (int dy = 0; dy < 3; ++dy) {
      const float* r = rowb + dy * 20;
      float v[6];
#pragma unroll
      for (int k = 0; k < 6; ++k) v[k] = r[k];
#pragma unroll
      for (int dx = 0; dx < 3; ++dx) {
        float wv = sW2[(ci * 9 + dy * 3 + dx) * 17 + co];
#pragma unroll
        for (int p = 0; p < 4; ++p) acc[p] = fmaf(v[p + dx], wv, acc[p]);
      }
    }
  }

  // skip 1x1 over 64 ci, staged in 4 chunks of 16 ci
  for (int cc = 0; cc < 4; ++cc) {
    __syncthreads();
    for (int idx = tid; idx < 16 * 8 * 16; idx += 512) {
      int ci = idx >> 7, r = idx & 127, iy = r >> 4, ix = r & 15;
      int gy = ty0 + iy, gx = tx0 + ix;
      float v = 0.f;
      if (gy < HH && gx < WWW) v = in[(cc * 16 + ci) * LL + gy * WWW + gx];
      sSkip[(ci * 8 + iy) * 17 + ix] = v;
    }
    __syncthreads();
    for (int c16 = 0; c16 < 16; ++c16) {
      float wv = sWs[(cc * 16 + c16) * 17 + co];
      const float* sv = &sSkip[(c16 * 8 + yl) * 17 + xq * 4];
#pragma unroll
      for (int p = 0; p < 4; ++p) acc[p] = fmaf(sv[p], wv, acc[p]);
    }
  }

  int yv = ty0 + yl;
  if (yv < HH) {
    float* Fb = F + (b * TL + src * LL + yv * WWW) * 16 + co;
#pragma unroll
    for (int p = 0; p < 4; ++p) {
      int xv = tx0 + xq * 4 + p;
      if (xv < WWW) Fb[xv * 16] = acc[p];
    }
  }
}

// Flat 320-block kernel, 576 threads:
//  blocks 0..279   : codes (35 segs x 8 bh); rot read uniform from global rotT
//  blocks 280..283 : rA/rB point-resblock (pre-transposed auxT, coalesced)
//  block  284      : per-batch E scalars
//  blocks 285..319 : inv permutation scatter
__global__ __launch_bounds__(576) void k_codes(
    const float* __restrict__ F, const float* __restrict__ rotT,
    const int* __restrict__ ri, unsigned char* __restrict__ codes,
    const float* __restrict__ fd1, const float* __restrict__ refin,
    const float* __restrict__ auxT,
    const float* __restrict__ a1b1, const float* __restrict__ a1b2,
    const float* __restrict__ a2b1, const float* __restrict__ a2b2,
    float* __restrict__ SC, int* __restrict__ inv) {
  int blk = blockIdx.x;
  int tid = threadIdx.x;

  if (blk < 280) {
    int bh = blk / 35, seg = blk % 35;
    int b = bh >> 2, h = bh & 3;
    int t = seg * 576 + tid;
    if (t >= TL) return;
    int pos = ri[t];
    const float* Fr = F + (b * TL + pos) * 16;
    float q[16];
#pragma unroll
    for (int c = 0; c < 16; ++c) q[c] = Fr[c];
    const float* rotb = rotT + h * 1024;   // wave-uniform -> scalar loads
    float best = -1e30f; int bi = 0;
    float worst = 1e30f; int wi = 0;
    for (int j = 0; j < 64; ++j) {
      float v = 0.f;
      const float* rp = rotb + j * 16;
#pragma unroll
      for (int c = 0; c < 16; ++c) v = fmaf(q[c], rp[c], v);
      if (v > best)  { best = v;  bi = j; }
      if (v < worst) { worst = v; wi = j; }
    }
    int code = (best >= -worst) ? bi : (64 + wi);
    codes[bh * TL + t] = (unsigned char)code;
    return;
  }

  if (blk >= 285) {   // inv scatter
    int t = (blk - 285) * 576 + tid;
    if (t < TL) {
      int p = ri[t];
      if (p < LL) inv[p] = t;
    }
    return;
  }

  if (blk == 284) {
#pragma clang fp contract(off)
    int b = tid;
    if (b >= BN) return;
    int j0 = ri[0], jL = ri[LL];
    const float* qA = F + (b * TL + j0) * 16;
    const float* qB = F + (b * TL + jL) * 16;
    float nA = 0.f, nB = 0.f;
    for (int c = 0; c < 16; ++c) { nA += qA[c] * qA[c]; nB += qB[c] * qB[c]; }
    float mA = fmaxf(sqrtf(nA), 5e-5f), mB = fmaxf(sqrtf(nB), 5e-5f);
    float d00 = 0.f, d01 = 0.f, d10 = 0.f, d11 = 0.f;
    for (int c = 0; c < 16; ++c) {
      float kAc = qA[c] / mA, kBc = qB[c] / mB;
      d00 += qA[c] * kAc; d01 += qA[c] * kBc;
      d10 += qB[c] * kAc; d11 += qB[c] * kBc;
    }
    float zA = (j0 < LL) ? 0.01f : 0.99f;
    float zB = (jL < LL) ? 0.01f : 0.99f;
    float* sc = SC + b * 136;
    sc[0] = expf(d00) * zA; sc[1] = expf(d01) * zB;
    sc[2] = expf(d10) * zA; sc[3] = expf(d11) * zB;
    return;
  }

  // point-resblock path (blocks 280..283), auxT pre-transposed (coalesced)
  int pb = blk - 280;
  int b = pb & 1, which = pb >> 1;
  int pos = ri[which * LL];
  const float *in, *w1T, *b1, *w2T, *b2;
  int sp;
  if (pos < LL) {
    in = fd1 + b * C0 * LL; w1T = auxT; b1 = a1b1; w2T = auxT + AUXW; b2 = a1b2; sp = pos;
  } else {
    in = refin + b * C0 * LL; w1T = auxT + 2 * AUXW; b1 = a2b1; w2T = auxT + 3 * AUXW;
    b2 = a2b2; sp = pos - LL;
  }
  int y = sp / WWW, x = sp % WWW;

  __shared__ float sPatch[64][25];
  __shared__ float sW[144 * 64];
  __shared__ float sH[9][64];
  __shared__ float sPart[9][64];

  for (int idx = tid; idx < 64 * 25; idx += 576) {
    int ci = idx / 25, pp = idx % 25;
    int gy = y - 2 + pp / 5, gx = x - 2 + pp % 5;
    float v = 0.f;
    if (gy >= 0 && gy < HH && gx >= 0 && gx < WWW) v = in[ci * LL + gy * WWW + gx];
    sPatch[ci][pp] = v;
  }

  int p = tid / 64, ch = tid & 63;
  int p3 = p / 3, pm = p % 3;
  int yy = y + p3 - 1, xx = x + pm - 1;
  bool inb = (yy >= 0) && (yy < HH) && (xx >= 0) && (xx < WWW);

  float acc0 = 0.f, acc1 = 0.f;
  for (int cc = 0; cc < 4; ++cc) {
    __syncthreads();
    for (int i = tid; i < 144 * 64; i += 576) sW[i] = w1T[cc * 9216 + i];
    __syncthreads();
    if (inb) {
#pragma unroll
      for (int ci = 0; ci < 16; ++ci) {
        const float* wp = &sW[ci * 9 * 64 + ch];
        const float* pr = &sPatch[cc * 16 + ci][0];
#pragma unroll
        for (int t = 0; t < 9; ++t) {
          float v = pr[(p3 + t / 3) * 5 + (pm + t % 3)];
          if (ci & 1) acc1 = fmaf(v, wp[t * 64], acc1);
          else        acc0 = fmaf(v, wp[t * 64], acc0);
        }
      }
    }
  }
  sH[p][ch] = inb ? fmaxf(acc0 + acc1 + b1[ch], 0.f) : 0.f;
  __syncthreads();

  {
    float part = 0.f;
    const float* wbase = w2T + p * 64 + ch;   // coalesced per-lane global reads
    for (int ci = 0; ci < 64; ++ci) part = fmaf(sH[p][ci], wbase[ci * 9 * 64], part);
    sPart[p][ch] = part;
  }
  __syncthreads();
  if (tid < 64) {
    int co = tid;
    float a = in[co * LL + y * WWW + x] + b2[co];
#pragma unroll
    for (int g = 0; g < 9; ++g) a += sPart[g][co];
    SC[b * 136 + 4 + which * 64 + co] = a;
  }
}

// stable counting sort per (b,h); hierarchical prefix (supergroups of 16) to
// avoid 240-long serial LDS chains; keys register-cached.
__global__ __launch_bounds__(256) void k_sort(
    const unsigned char* __restrict__ codes,
    int* __restrict__ rank_of, int* __restrict__ n0g) {
  int bh = blockIdx.x;
  const unsigned int* keys4 = (const unsigned int*)(codes + bh * TL);
  __shared__ unsigned short cnt[128 * 241];   // [class][group], pad 241
  __shared__ unsigned int sup[128 * 16];      // per-class supergroup partial/scan
  __shared__ unsigned int totalsL[128];
  __shared__ unsigned int baseoff[128];
  __shared__ unsigned int n0s[NCHK];
  __shared__ unsigned int wtot;
  int tid = threadIdx.x;

  for (int i = tid; i < 128 * 241 / 2; i += 256) ((unsigned int*)cnt)[i] = 0u;
  for (int i = tid; i < NCHK; i += 256) n0s[i] = 0u;
  __syncthreads();

  const int SEG = 84;
  int base = tid * SEG;
  int nloc = (tid < 240) ? (TL - base) : 0;
  if (nloc > SEG) nloc = SEG;
  if (nloc < 0) nloc = 0;

  // load keys once into registers (u32 words; base is 4B aligned)
  unsigned int kw[21];
  int nw = (nloc + 3) >> 2;
  for (int w = 0; w < nw; ++w) kw[w] = keys4[tid * 21 + w];

  // Phase 1: count
  for (int e = 0; e < nloc; ++e) {
    int c = (kw[e >> 2] >> ((e & 3) * 8)) & 255;
    cnt[c * 241 + tid]++;
  }
  __syncthreads();

  // Phase 2a: supergroup partial sums (15 supergroups of 16 groups)
  for (int idx = tid; idx < 128 * 15; idx += 256) {
    int c = idx / 15, s = idx % 15;
    unsigned int sum = 0;
#pragma unroll
    for (int k = 0; k < 16; ++k) sum += cnt[c * 241 + 16 * s + k];
    sup[c * 16 + s] = sum;
  }
  __syncthreads();

  // Phase 2b: exclusive scan over supergroups per class (15-long, 128 parallel)
  if (tid < 128) {
    unsigned int run = 0;
#pragma unroll
    for (int s = 0; s < 15; ++s) {
      unsigned int t = sup[tid * 16 + s];
      sup[tid * 16 + s] = run;
      run += t;
    }
    totalsL[tid] = run;
  }
  __syncthreads();

  // Phase 2c: baseoff = exclusive scan of totals over classes (wave shfl scan)
  {
    unsigned int v = 0;
    if (tid < 128) {
      v = totalsL[tid];
#pragma unroll
      for (int d = 1; d < 64; d <<= 1) {
        unsigned int o = __shfl_up(v, d);
        if ((tid & 63) >= d) v += o;
      }
      if (tid == 63) wtot = v;
    }
    __syncthreads();
    if (tid < 128) {
      unsigned int incl = v + ((tid >= 64) ? wtot : 0u);
      baseoff[tid] = incl - totalsL[tid];
    }
  }
  __syncthreads();

  // Phase 3: final per-group offsets written back into cnt (16-long chains)
  for (int idx = tid; idx < 128 * 15; idx += 256) {
    int c = idx / 15, s = idx % 15;
    unsigned int run = baseoff[c] + sup[c * 16 + s];
#pragma unroll
    for (int k = 0; k < 16; ++k) {
      int g = 16 * s + k;
      unsigned int t = cnt[c * 241 + g];
      cnt[c * 241 + g] = (unsigned short)run;
      run += t;
    }
  }
  __syncthreads();

  // Phase 4: placement (stable within segment), n0 histogram
  for (int e = 0; e < nloc; ++e) {
    int idx = base + e;
    int c = (kw[e >> 2] >> ((e & 3) * 8)) & 255;
    unsigned int r = cnt[c * 241 + tid]++;
    rank_of[bh * TL + idx] = (int)r;
    if (!(idx & 1)) {
      atomicAdd(&n0s[r / CHK], 1u);
      if (r >= TL - NPAD) atomicAdd(&n0s[NCHK - 1], 1u);
    }
  }
  __syncthreads();
  for (int i = tid; i < NCHK; i += 256) n0g[bh * NCHK + i] = (int)n0s[i];
}

// out[b][c][p]: t = inv[p]; alpha/beta computed inline from rank_of/n0.
// c-split 4 ways (blockIdx.z) for occupancy on this gather-latency-bound kernel.
__global__ __launch_bounds__(256) void k_out(
    const int* __restrict__ inv, const int* __restrict__ rank_of,
    const int* __restrict__ n0, const float* __restrict__ SC,
    float* __restrict__ out) {
  int b = blockIdx.y;
  int c0 = blockIdx.z * 16;
  int p = blockIdx.x * 256 + threadIdx.x;
  if (p >= LL) return;
  int t = inv[p];
  int si = t & 1;
  float e0 = SC[b * 136 + si * 2 + 0];
  float e1 = SC[b * 136 + si * 2 + 1];
  float s0 = 0.f, s1 = 0.f;
  for (int h = 0; h < 4; ++h) {
    int r = rank_of[(b * 4 + h) * TL + t];
    int k = r / CHK;
    int km = (k == 0) ? NCHK - 1 : k - 1;
    int kp = (k == NCHK - 1) ? 0 : k + 1;
    const int* nb = n0 + (b * 4 + h) * NCHK;
    int W0 = nb[k] + nb[km] + nb[kp];
    s0 += (float)W0 * e0;
    s1 += (float)(WINR - W0) * e1;
  }
  float invd = 1.f / (s0 + s1);
  float al = s0 * invd;
  float be = s1 * invd;
  const float* rA = SC + b * 136 + 4;
  const float* rB = rA + 64;
  float* o = out + b * C0 * LL + p;
#pragma unroll
  for (int c = 0; c < 16; ++c) o[(c0 + c) * LL] = al * rA[c0 + c] + be * rB[c0 + c];
}

}  // namespace

extern "C" void kernel_launch(void* const* d_in, const int* in_sizes, int n_in,
                              void* d_out, int out_size, void* d_ws, size_t ws_size,
                              hipStream_t stream) {
  const float* fd1  = (const float*)d_in[0];
  const float* fd2  = (const float*)d_in[1];
  const float* reff = (const float*)d_in[2];
  const int*   ri   = (const int*)d_in[3];
  const float* mw1  = (const float*)d_in[4];
  const float* mb1  = (const float*)d_in[5];
  const float* mw2  = (const float*)d_in[6];
  const float* mb2  = (const float*)d_in[7];
  const float* mws  = (const float*)d_in[8];
  const float* mbs  = (const float*)d_in[9];
  const float* a1w1 = (const float*)d_in[10];
  const float* a1b1 = (const float*)d_in[11];
  const float* a1w2 = (const float*)d_in[12];
  const float* a1b2 = (const float*)d_in[13];
  const float* a2w1 = (const float*)d_in[14];
  const float* a2b1 = (const float*)d_in[15];
  const float* a2w2 = (const float*)d_in[16];
  const float* a2b2 = (const float*)d_in[17];

  float* ws = (float*)d_ws;
  float* ht0  = ws + OFF_HT0;
  float* ht1  = ws + OFF_HT1;
  float* ht2  = ws + OFF_HT2;
  float* ht3  = ws + OFF_HT3;
  float* F    = ws + OFF_F;
  float* SC   = ws + OFF_SC;
  unsigned char* codes = (unsigned char*)(ws + OFF_CODE);
  int* rank_of = (int*)(ws + OFF_RANK);
  int* n0      = (int*)(ws + OFF_N0);
  int* invp    = (int*)(ws + OFF_INV);
  float* auxT  = ws + OFF_AUX;
  float* rotT  = ws + OFF_ROT;

  k_conv1<<<dim3(1752), dim3(512), 0, stream>>>(fd1, fd2, mw1, a1w1, a1w2, a2w1,
                                                a2w2, ht0, ht1, ht2, ht3, auxT, rotT);
  k_conv2<<<dim3(364), dim3(512), 0, stream>>>(fd1, fd2, ht0, ht1, ht2, ht3, mw2,
                                               mb1, mb2, mws, mbs, F);
  k_codes<<<dim3(320), dim3(576), 0, stream>>>(F, rotT, ri, codes, fd1, reff, auxT,
                                               a1b1, a1b2, a2b1, a2b2, SC, invp);
  k_sort<<<dim3(8), dim3(256), 0, stream>>>(codes, rank_of, n0);
  k_out<<<dim3(40, 2, 4), dim3(256), 0, stream>>>(invp, rank_of, n0, SC, (float*)d_out);
}